// Round 1
// 213.805 us; speedup vs baseline: 1.0578x; 1.0578x over previous
//
#include <hip/hip_runtime.h>

#define EMBED 1024
#define NHEADS 16
#define HDIM 64
#define SEQ 2048
#define BATCH 2
#define MROWS (BATCH * SEQ)   // 4096

using bf16x8 = __attribute__((ext_vector_type(8))) short;
using f32x4  = __attribute__((ext_vector_type(4))) float;
using us4    = __attribute__((ext_vector_type(4))) unsigned short;
using u32x2  = __attribute__((ext_vector_type(2))) unsigned int;

__device__ __forceinline__ unsigned short f2bf(float f) {
    unsigned int u = __builtin_bit_cast(unsigned int, f);
    u = (u + 0x7fffu + ((u >> 16) & 1u)) >> 16;   // RNE
    return (unsigned short)u;
}

// HW packed f32->bf16 (RNE). No builtin on gfx950 -> inline asm (non-volatile
// so the scheduler can move it freely).
__device__ __forceinline__ unsigned int cvt_pk_bf16(float a, float b) {
    unsigned int d;
    asm("v_cvt_pk_bf16_f32 %0, %1, %2" : "=v"(d) : "v"(a), "v"(b));
    return d;
}

__device__ __forceinline__ void async16(const unsigned short* g, unsigned short* l) {
    __builtin_amdgcn_global_load_lds(
        (const __attribute__((address_space(1))) void*)g,
        (__attribute__((address_space(3))) void*)l, 16, 0, 0);
}

// ---------------------------------------------------------------------------
// convert x (fp32 [4096][1024]) -> bf16, 4 elems/thread
// ---------------------------------------------------------------------------
__global__ __launch_bounds__(256)
void cvt_x(const float* __restrict__ in, unsigned short* __restrict__ out)
{
    int i = blockIdx.x * 256 + threadIdx.x;
    float4 v = ((const float4*)in)[i];
    us4 o;
    o[0] = f2bf(v.x); o[1] = f2bf(v.y); o[2] = f2bf(v.z); o[3] = f2bf(v.w);
    ((us4*)out)[i] = o;
}

// ---------------------------------------------------------------------------
// convert + transpose weights: W fp32 [k][n] -> Wt bf16 [n][k]. 64x64 tiles.
// ---------------------------------------------------------------------------
__global__ __launch_bounds__(256)
void cvt_w(const float* __restrict__ W0, const float* __restrict__ W1,
           const float* __restrict__ W2, const float* __restrict__ W3,
           unsigned short* __restrict__ T0, unsigned short* __restrict__ T1,
           unsigned short* __restrict__ T2, unsigned short* __restrict__ T3)
{
    const float* W = blockIdx.z == 0 ? W0 : blockIdx.z == 1 ? W1 :
                     blockIdx.z == 2 ? W2 : W3;
    unsigned short* T = blockIdx.z == 0 ? T0 : blockIdx.z == 1 ? T1 :
                        blockIdx.z == 2 ? T2 : T3;
    __shared__ unsigned short tile[64][72];
    const int tid = threadIdx.x;
    const int k0 = blockIdx.y << 6, n0 = blockIdx.x << 6;
    const int lr = tid >> 4, lc = (tid & 15) << 2;
#pragma unroll
    for (int it = 0; it < 4; ++it) {
        int kr = lr + it * 16;
        float4 v = *(const float4*)(W + (size_t)(k0 + kr) * EMBED + n0 + lc);
        tile[lc + 0][kr] = f2bf(v.x);
        tile[lc + 1][kr] = f2bf(v.y);
        tile[lc + 2][kr] = f2bf(v.z);
        tile[lc + 3][kr] = f2bf(v.w);
    }
    __syncthreads();
#pragma unroll
    for (int it = 0; it < 4; ++it) {
        int nr = lr + it * 16;
        us4 o = *(const us4*)(&tile[nr][lc]);
        *(us4*)(T + (size_t)(n0 + nr) * EMBED + k0 + lc) = o;
    }
}

// ---------------------------------------------------------------------------
// MFMA GEMM core 128x128 (unchanged)
// ---------------------------------------------------------------------------
__device__ __forceinline__ void mfma_gemm_core(
    const unsigned short* __restrict__ A, const unsigned short* __restrict__ Bt,
    int bm, int n0, unsigned short* As, unsigned short* Bs,
    int wv, int lane, f32x4 acc[4][4])
{
    const int m16 = lane & 15, quad = lane >> 4;
    const int mb = (wv >> 1) << 6;
    const int nb = (wv & 1) << 6;

    const unsigned short* ga = A  + (size_t)(bm + wv * 32 + (lane >> 3)) * EMBED + ((lane & 7) << 3);
    const unsigned short* gb = Bt + (size_t)(n0 + wv * 32 + (lane >> 3)) * EMBED + ((lane & 7) << 3);
    unsigned short* la = As + wv * 32 * 64;
    unsigned short* lb = Bs + wv * 32 * 64;

    for (int k0 = 0; k0 < EMBED; k0 += 64) {
        __syncthreads();
#pragma unroll
        for (int j = 0; j < 4; ++j) {
            async16(ga + j * 8 * EMBED, la + j * 8 * 64);
            async16(gb + j * 8 * EMBED, lb + j * 8 * 64);
        }
        ga += 64; gb += 64;
        __syncthreads();
#pragma unroll
        for (int ks = 0; ks < 2; ++ks) {
            const int ko = ks * 32 + (quad << 3);
            bf16x8 af[4], bfv[4];
#pragma unroll
            for (int i = 0; i < 4; ++i) {
                af[i]  = *(const bf16x8*)(As + (mb + i * 16 + m16) * 64 + ko);
                bfv[i] = *(const bf16x8*)(Bs + (nb + i * 16 + m16) * 64 + ko);
            }
#pragma unroll
            for (int i = 0; i < 4; ++i)
#pragma unroll
                for (int j = 0; j < 4; ++j)
                    acc[i][j] = __builtin_amdgcn_mfma_f32_16x16x32_bf16(
                        af[i], bfv[j], acc[i][j], 0, 0, 0);
        }
    }
}

// ---------------------------------------------------------------------------
// MFMA GEMM core 128x64 (for out_gemm: more blocks)
// ---------------------------------------------------------------------------
__device__ __forceinline__ void mfma_gemm_core64(
    const unsigned short* __restrict__ A, const unsigned short* __restrict__ Bt,
    int bm, int n0, unsigned short* As, unsigned short* Bs,
    int wv, int lane, f32x4 acc[4][2])
{
    const int m16 = lane & 15, quad = lane >> 4;
    const int mb = (wv >> 1) << 6;
    const int nb = (wv & 1) << 5;

    const unsigned short* ga = A  + (size_t)(bm + wv * 32 + (lane >> 3)) * EMBED + ((lane & 7) << 3);
    const unsigned short* gb = Bt + (size_t)(n0 + wv * 16 + (lane >> 3)) * EMBED + ((lane & 7) << 3);
    unsigned short* la = As + wv * 32 * 64;
    unsigned short* lb = Bs + wv * 16 * 64;

    for (int k0 = 0; k0 < EMBED; k0 += 64) {
        __syncthreads();
#pragma unroll
        for (int j = 0; j < 4; ++j)
            async16(ga + j * 8 * EMBED, la + j * 8 * 64);
#pragma unroll
        for (int j = 0; j < 2; ++j)
            async16(gb + j * 8 * EMBED, lb + j * 8 * 64);
        ga += 64; gb += 64;
        __syncthreads();
#pragma unroll
        for (int ks = 0; ks < 2; ++ks) {
            const int ko = ks * 32 + (quad << 3);
            bf16x8 af[4], bfv[2];
#pragma unroll
            for (int i = 0; i < 4; ++i)
                af[i] = *(const bf16x8*)(As + (mb + i * 16 + m16) * 64 + ko);
#pragma unroll
            for (int j = 0; j < 2; ++j)
                bfv[j] = *(const bf16x8*)(Bs + (nb + j * 16 + m16) * 64 + ko);
#pragma unroll
            for (int i = 0; i < 4; ++i)
#pragma unroll
                for (int j = 0; j < 2; ++j)
                    acc[i][j] = __builtin_amdgcn_mfma_f32_16x16x32_bf16(
                        af[i], bfv[j], acc[i][j], 0, 0, 0);
        }
    }
}

// ---------------------------------------------------------------------------
// Fused QKV projection (unchanged)
// ---------------------------------------------------------------------------
__global__ __launch_bounds__(256)
void qkv_gemm(const unsigned short* __restrict__ xb,
              const unsigned short* __restrict__ Wtq,
              const unsigned short* __restrict__ Wtk,
              const unsigned short* __restrict__ Wtv,
              const float* __restrict__ bq, const float* __restrict__ bk,
              const float* __restrict__ bv,
              unsigned short* __restrict__ Qo, unsigned short* __restrict__ Ko,
              unsigned short* __restrict__ Vto)
{
    __shared__ __align__(16) unsigned short As[128 * 64];
    __shared__ __align__(16) unsigned short Bs[128 * 64];
    const int tid = threadIdx.x, wv = tid >> 6, lane = tid & 63;
    const int m16 = lane & 15, quad = lane >> 4;
    const int which = blockIdx.x >> 3;
    const int n0 = (blockIdx.x & 7) << 7;
    const int bm = blockIdx.y << 7;
    const unsigned short* Bt = which == 0 ? Wtq : which == 1 ? Wtk : Wtv;
    const float* bias = which == 0 ? bq : which == 1 ? bk : bv;

    f32x4 acc[4][4];
#pragma unroll
    for (int i = 0; i < 4; ++i)
#pragma unroll
        for (int j = 0; j < 4; ++j) acc[i][j] = (f32x4){0.f, 0.f, 0.f, 0.f};

    mfma_gemm_core(xb, Bt, bm, n0, As, Bs, wv, lane, acc);

    const int mb = (wv >> 1) << 6, nb = (wv & 1) << 6;
    const float qscale = 0.125f * 1.4426950408889634f;
#pragma unroll
    for (int i = 0; i < 4; ++i) {
        const int m0 = bm + mb + i * 16 + quad * 4;
        const int b = m0 >> 11, t0 = m0 & (SEQ - 1);
#pragma unroll
        for (int j = 0; j < 4; ++j) {
            const int n = n0 + nb + j * 16 + m16;
            const int h = n >> 6, d = n & 63;
            const float bval = bias[n];
            if (which == 2) {
                us4 v;
#pragma unroll
                for (int r = 0; r < 4; ++r) v[r] = f2bf(acc[i][j][r] + bval);
                *(us4*)(Vto + ((((size_t)(b * NHEADS + h)) << 6) + d) * SEQ + t0) = v;
            } else {
                const float sc = which == 0 ? qscale : 1.f;
                unsigned short* dst = (which == 0 ? Qo : Ko) +
                    ((((size_t)(b * NHEADS + h)) << 11) + t0) * 64 + d;
#pragma unroll
                for (int r = 0; r < 4; ++r)
                    dst[(size_t)r * 64] = f2bf((acc[i][j][r] + bval) * sc);
            }
        }
    }
}

// ---------------------------------------------------------------------------
// Output projection: out fp32 = ao_bf16 @ Wo + bo. 128x64 tile, 512 blocks.
// ---------------------------------------------------------------------------
__global__ __launch_bounds__(256)
void out_gemm(const unsigned short* __restrict__ aob,
              const unsigned short* __restrict__ Wto,
              const float* __restrict__ bo, float* __restrict__ out)
{
    __shared__ __align__(16) unsigned short As[128 * 64];
    __shared__ __align__(16) unsigned short Bs[64 * 64];
    const int tid = threadIdx.x, wv = tid >> 6, lane = tid & 63;
    const int m16 = lane & 15, quad = lane >> 4;
    const int n0 = blockIdx.x << 6;
    const int bm = blockIdx.y << 7;

    f32x4 acc[4][2];
#pragma unroll
    for (int i = 0; i < 4; ++i)
#pragma unroll
        for (int j = 0; j < 2; ++j) acc[i][j] = (f32x4){0.f, 0.f, 0.f, 0.f};

    mfma_gemm_core64(aob, Wto, bm, n0, As, Bs, wv, lane, acc);

    const int mb = (wv >> 1) << 6, nb = (wv & 1) << 5;
#pragma unroll
    for (int i = 0; i < 4; ++i) {
        const int m0 = bm + mb + i * 16 + quad * 4;
#pragma unroll
        for (int j = 0; j < 2; ++j) {
            const int n = n0 + nb + j * 16 + m16;
            const float bval = bo[n];
#pragma unroll
            for (int r = 0; r < 4; ++r)
                out[(size_t)(m0 + r) * EMBED + n] = acc[i][j][r] + bval;
        }
    }
}

// ---------------------------------------------------------------------------
// bf16 MFMA flash attention, operand-swapped (S^T = K·Q^T, O^T = V^T·P^T).
// Round-4 changes:
//  * grid 512 -> 1024 blocks (one 64-query tile per block). blockIdx.x = bh
//    so same-bh blocks co-reside on a CU/XCD (K/V L2 locality). blockIdx.y
//    maps to qt via a permutation giving each CU (ids c,c+256,c+512,c+768
//    under round-robin) qt ∈ {r,15-r,16+r,31-r} => constant 66 iters/CU.
//  * LDS 46 -> 40 KB exactly (4 blocks/CU): drop +8 pad on K/V/Ps, use
//    XOR slot-swizzle (16B slot ^= row&7) instead. All b128 LDS ops stay at
//    the structural-minimum 8-lanes-per-bank-group distribution.
//  * VALU cuts: v_cvt_pk_bf16_f32 for P/O packing (16 f2bf -> 8 instrs),
//    defer-max rescale with THR=8 (skip O-rescale when max stable).
// ---------------------------------------------------------------------------
__global__ __launch_bounds__(256)
void attn_mfma(const unsigned short* __restrict__ Qb,
               const unsigned short* __restrict__ Kb,
               const unsigned short* __restrict__ Vtb,
               unsigned short* __restrict__ Oout)
{
    __shared__ __align__(16) unsigned short Ks[2][64 * 64];   // [key][d]  swz
    __shared__ __align__(16) unsigned short Vt[2][64 * 64];   // [d][key]  swz
    __shared__ __align__(16) unsigned short Ps[4][16 * 64];   // [query][key] swz

    const int tid  = threadIdx.x;
    const int wv   = tid >> 6;
    const int lane = tid & 63;
    const int m16  = lane & 15;
    const int quad = lane >> 4;
    const int bh   = blockIdx.x;
    const int b    = bh >> 4, h = bh & 15;

    // balanced qt permutation: y = r + 8k -> qt in {r, 15-r, 16+r, 31-r}
    const int yr = blockIdx.y & 7, yk = blockIdx.y >> 3;
    const int qt = yk == 0 ? yr : yk == 1 ? 15 - yr : yk == 2 ? 16 + yr : 31 - yr;
    const int q0 = qt << 6;

    const int srow = tid >> 2;         // 0..63
    const int cc   = tid & 3;          // 16B-slot pair index
    const int swr  = srow & 7;         // write-side swizzle
    const int sx   = m16 & 7;          // read-side swizzle (row % 8)

    bf16x8 rk0, rk1, rv0, rv1;
    auto load_tile = [&](int k0) {
        const int scol = cc << 4;
        const unsigned short* sk = Kb + (((size_t)bh << 11) + k0 + srow) * 64 + scol;
        rk0 = *(const bf16x8*)sk;
        rk1 = *(const bf16x8*)(sk + 8);
        const unsigned short* sv = Vtb + (((size_t)bh << 6) + srow) * SEQ + k0 + scol;
        rv0 = *(const bf16x8*)sv;
        rv1 = *(const bf16x8*)(sv + 8);
    };

    // Q fragment (B operand): lane n = query = m16, k = d
    const size_t qoff =
        (((size_t)bh << 11) + q0 + (wv << 4) + m16) * 64 + (quad << 3);
    bf16x8 qa0 = *(const bf16x8*)(Qb + qoff);
    bf16x8 qa1 = *(const bf16x8*)(Qb + qoff + 32);

    f32x4 o[4];
#pragma unroll
    for (int dt = 0; dt < 4; ++dt) o[dt] = (f32x4){0.f, 0.f, 0.f, 0.f};
    float m_ = -1e30f, l_ = 0.f;

    load_tile(0);

    for (int kt = 0; kt <= qt; ++kt) {
        unsigned short* Kp = Ks[kt & 1];
        unsigned short* Vp = Vt[kt & 1];
        {
            unsigned short* kd = Kp + srow * 64;
            unsigned short* vd = Vp + srow * 64;
            *(bf16x8*)(kd + (((2 * cc) ^ swr) << 3))     = rk0;
            *(bf16x8*)(kd + (((2 * cc + 1) ^ swr) << 3)) = rk1;
            *(bf16x8*)(vd + (((2 * cc) ^ swr) << 3))     = rv0;
            *(bf16x8*)(vd + (((2 * cc + 1) ^ swr) << 3)) = rv1;
        }
        __syncthreads();
        if (kt < qt) load_tile((kt + 1) << 6);

        const bool diag = (kt == qt);

        // S^T = K·Q^T: D[key=g*16+quad*4+r][query=m16]
        f32x4 s[4];
#pragma unroll
        for (int g = 0; g < 4; ++g) {
            if (diag && g > wv) {
                s[g] = (f32x4){-1e30f, -1e30f, -1e30f, -1e30f};
                continue;
            }
            const unsigned short* kr = Kp + (g * 16 + m16) * 64;
            bf16x8 kb0 = *(const bf16x8*)(kr + ((quad ^ sx) << 3));
            bf16x8 kb1 = *(const bf16x8*)(kr + (((quad + 4) ^ sx) << 3));
            s[g] = (f32x4){0.f, 0.f, 0.f, 0.f};
            s[g] = __builtin_amdgcn_mfma_f32_16x16x32_bf16(kb0, qa0, s[g], 0, 0, 0);
            s[g] = __builtin_amdgcn_mfma_f32_16x16x32_bf16(kb1, qa1, s[g], 0, 0, 0);
        }
        if (diag) {
#pragma unroll
            for (int r = 0; r < 4; ++r)
                if (quad * 4 + r > m16) s[wv][r] = -1e30f;
        }

        // online softmax; all 16 scores belong to query m16
        float mx = fmaxf(fmaxf(s[0][0], s[0][1]), fmaxf(s[0][2], s[0][3]));
#pragma unroll
        for (int g = 1; g < 4; ++g)
            mx = fmaxf(mx, fmaxf(fmaxf(s[g][0], s[g][1]), fmaxf(s[g][2], s[g][3])));
        mx = fmaxf(mx, __shfl_xor(mx, 16));
        mx = fmaxf(mx, __shfl_xor(mx, 32));

        // defer-max: only rescale when tile max grows by > 8 (P bounded 2^8)
        if (mx > m_ + 8.f) {
            const float alpha = exp2f(m_ - mx);
            m_ = mx;
            l_ *= alpha;
#pragma unroll
            for (int dt = 0; dt < 4; ++dt) o[dt] *= alpha;
        }

        float sum = 0.f;
        unsigned int pw0[4], pw1[4];
#pragma unroll
        for (int g = 0; g < 4; ++g) {
            float p0 = exp2f(s[g][0] - m_);
            float p1 = exp2f(s[g][1] - m_);
            float p2 = exp2f(s[g][2] - m_);
            float p3 = exp2f(s[g][3] - m_);
            sum += (p0 + p1) + (p2 + p3);
            pw0[g] = cvt_pk_bf16(p0, p1);
            pw1[g] = cvt_pk_bf16(p2, p3);
        }
        sum += __shfl_xor(sum, 16);
        sum += __shfl_xor(sum, 32);
        l_ += sum;

        // P^T -> Ps[query][key]: key-words g*8+quad*2+{0,1} => 16B slot
        // 2g+(quad>>1), 8B parity quad&1, slot ^= m16&7
        {
            unsigned short* pd = Ps[wv] + m16 * 64 + ((quad & 1) << 2);
#pragma unroll
            for (int g = 0; g < 4; ++g) {
                u32x2 w; w.x = pw0[g]; w.y = pw1[g];
                *(u32x2*)(pd + (((2 * g + (quad >> 1)) ^ sx) << 3)) = w;
            }
        }

        // O^T += V^T·P^T: A = V^T-frag, B = P^T-frag
        const unsigned short* pr = Ps[wv] + m16 * 64;
        bf16x8 pa0 = *(const bf16x8*)(pr + ((quad ^ sx) << 3));
        bf16x8 pa1 = *(const bf16x8*)(pr + (((quad + 4) ^ sx) << 3));
        const bool skip_hi = diag && (wv < 2);   // keys 32..63 all masked
#pragma unroll
        for (int dt = 0; dt < 4; ++dt) {
            const unsigned short* vr = Vp + (dt * 16 + m16) * 64;
            bf16x8 vb0 = *(const bf16x8*)(vr + ((quad ^ sx) << 3));
            o[dt] = __builtin_amdgcn_mfma_f32_16x16x32_bf16(vb0, pa0, o[dt], 0, 0, 0);
            if (!skip_hi) {
                bf16x8 vb1 = *(const bf16x8*)(vr + (((quad + 4) ^ sx) << 3));
                o[dt] = __builtin_amdgcn_mfma_f32_16x16x32_bf16(vb1, pa1, o[dt], 0, 0, 0);
            }
        }
    }

    // epilogue: lane m16 = query t, holds d = dt*16 + quad*4 + r
    const float inv = 1.f / l_;
    const int t = q0 + (wv << 4) + m16;
    unsigned short* dst =
        Oout + ((size_t)((b << 11) + t) << 10) + (h << 6) + (quad << 2);
#pragma unroll
    for (int dt = 0; dt < 4; ++dt) {
        u32x2 w;
        w.x = cvt_pk_bf16(o[dt][0] * inv, o[dt][1] * inv);
        w.y = cvt_pk_bf16(o[dt][2] * inv, o[dt][3] * inv);
        *(u32x2*)(dst + dt * 16) = w;
    }
}

extern "C" void kernel_launch(void* const* d_in, const int* in_sizes, int n_in,
                              void* d_out, int out_size, void* d_ws, size_t ws_size,
                              hipStream_t stream) {
    const float* x  = (const float*)d_in[0];
    const float* Wq = (const float*)d_in[1];
    const float* bq = (const float*)d_in[2];
    const float* Wk = (const float*)d_in[3];
    const float* bk = (const float*)d_in[4];
    const float* Wv = (const float*)d_in[5];
    const float* bv = (const float*)d_in[6];
    const float* Wo = (const float*)d_in[7];
    const float* bo = (const float*)d_in[8];
    float* out = (float*)d_out;

    const size_t HSZ = (size_t)MROWS * EMBED;   // 4M elems
    const size_t WSZ = (size_t)EMBED * EMBED;   // 1M elems
    unsigned short* qb  = (unsigned short*)d_ws;
    unsigned short* kb  = qb + HSZ;
    unsigned short* vtb = kb + HSZ;
    unsigned short* aob = vtb + HSZ;
    unsigned short* xb  = aob + HSZ;
    unsigned short* wtq = xb + HSZ;
    unsigned short* wtk = wtq + WSZ;
    unsigned short* wtv = wtk + WSZ;
    unsigned short* wto = wtv + WSZ;

    cvt_x<<<MROWS * EMBED / 1024, 256, 0, stream>>>(x, xb);
    cvt_w<<<dim3(16, 16, 4), 256, 0, stream>>>(Wq, Wk, Wv, Wo, wtq, wtk, wtv, wto);

    qkv_gemm<<<dim3(24, 32), 256, 0, stream>>>(xb, wtq, wtk, wtv, bq, bk, bv,
                                               qb, kb, vtb);

    attn_mfma<<<dim3(32, 32), 256, 0, stream>>>(qb, kb, vtb, aob);

    out_gemm<<<dim3(16, 32), 256, 0, stream>>>(aob, wto, bo, out);
}

// Round 3
// 202.841 us; speedup vs baseline: 1.1149x; 1.0540x over previous
//
#include <hip/hip_runtime.h>

#define EMBED 1024
#define NHEADS 16
#define HDIM 64
#define SEQ 2048
#define BATCH 2
#define MROWS (BATCH * SEQ)   // 4096

using bf16x8 = __attribute__((ext_vector_type(8))) short;
using f32x4  = __attribute__((ext_vector_type(4))) float;
using us4    = __attribute__((ext_vector_type(4))) unsigned short;
using u32x2  = __attribute__((ext_vector_type(2))) unsigned int;

__device__ __forceinline__ unsigned short f2bf(float f) {
    unsigned int u = __builtin_bit_cast(unsigned int, f);
    u = (u + 0x7fffu + ((u >> 16) & 1u)) >> 16;   // RNE
    return (unsigned short)u;
}

// HW packed f32->bf16 (RNE). No builtin on gfx950 -> inline asm.
__device__ __forceinline__ unsigned int cvt_pk_bf16(float a, float b) {
    unsigned int d;
    asm("v_cvt_pk_bf16_f32 %0, %1, %2" : "=v"(d) : "v"(a), "v"(b));
    return d;
}

__device__ __forceinline__ void async16(const unsigned short* g, unsigned short* l) {
    __builtin_amdgcn_global_load_lds(
        (const __attribute__((address_space(1))) void*)g,
        (__attribute__((address_space(3))) void*)l, 16, 0, 0);
}

// ---------------------------------------------------------------------------
// convert x (fp32 [4096][1024]) -> bf16, 4 elems/thread
// ---------------------------------------------------------------------------
__global__ __launch_bounds__(256)
void cvt_x(const float* __restrict__ in, unsigned short* __restrict__ out)
{
    int i = blockIdx.x * 256 + threadIdx.x;
    float4 v = ((const float4*)in)[i];
    us4 o;
    o[0] = f2bf(v.x); o[1] = f2bf(v.y); o[2] = f2bf(v.z); o[3] = f2bf(v.w);
    ((us4*)out)[i] = o;
}

// ---------------------------------------------------------------------------
// convert + transpose weights: W fp32 [k][n] -> Wt bf16 [n][k]. 64x64 tiles.
// ---------------------------------------------------------------------------
__global__ __launch_bounds__(256)
void cvt_w(const float* __restrict__ W0, const float* __restrict__ W1,
           const float* __restrict__ W2, const float* __restrict__ W3,
           unsigned short* __restrict__ T0, unsigned short* __restrict__ T1,
           unsigned short* __restrict__ T2, unsigned short* __restrict__ T3)
{
    const float* W = blockIdx.z == 0 ? W0 : blockIdx.z == 1 ? W1 :
                     blockIdx.z == 2 ? W2 : W3;
    unsigned short* T = blockIdx.z == 0 ? T0 : blockIdx.z == 1 ? T1 :
                        blockIdx.z == 2 ? T2 : T3;
    __shared__ unsigned short tile[64][72];
    const int tid = threadIdx.x;
    const int k0 = blockIdx.y << 6, n0 = blockIdx.x << 6;
    const int lr = tid >> 4, lc = (tid & 15) << 2;
#pragma unroll
    for (int it = 0; it < 4; ++it) {
        int kr = lr + it * 16;
        float4 v = *(const float4*)(W + (size_t)(k0 + kr) * EMBED + n0 + lc);
        tile[lc + 0][kr] = f2bf(v.x);
        tile[lc + 1][kr] = f2bf(v.y);
        tile[lc + 2][kr] = f2bf(v.z);
        tile[lc + 3][kr] = f2bf(v.w);
    }
    __syncthreads();
#pragma unroll
    for (int it = 0; it < 4; ++it) {
        int nr = lr + it * 16;
        us4 o = *(const us4*)(&tile[nr][lc]);
        *(us4*)(T + (size_t)(n0 + nr) * EMBED + k0 + lc) = o;
    }
}

// ---------------------------------------------------------------------------
// MFMA GEMM core 128x128: LDS double-buffer + counted vmcnt + raw s_barrier
// (loads stay in flight across barriers), XOR-swizzled LDS via pre-swizzled
// GLOBAL source (global_load_lds writes linearly; both-sides swizzle =>
// read slot (ks*4+quad)^(row&7)). Conflict-free ds_read_b128.
// ---------------------------------------------------------------------------
__device__ __forceinline__ void mfma_gemm_core(
    const unsigned short* __restrict__ A, const unsigned short* __restrict__ Bt,
    int bm, int n0, unsigned short* As, unsigned short* Bs,
    int wv, int lane, f32x4 acc[4][4])
{
    const int m16 = lane & 15, quad = lane >> 4;
    const int mb = (wv >> 1) << 6;
    const int nb = (wv & 1) << 6;
    const int rsw = m16 & 7;

    // pre-swizzled global column: LDS[row][s] ends up holding logical
    // (row, s ^ (row&7)); row&7 == (lane>>3)&7 for every staged sub-row.
    const int gcol = ((lane & 7) ^ ((lane >> 3) & 7)) << 3;
    const unsigned short* ga = A  + (size_t)(bm + wv * 32 + (lane >> 3)) * EMBED + gcol;
    const unsigned short* gb = Bt + (size_t)(n0 + wv * 32 + (lane >> 3)) * EMBED + gcol;

    // per-thread ds offsets (elements)
    int offA[4], offB[4];
#pragma unroll
    for (int i = 0; i < 4; ++i) {
        offA[i] = (mb + i * 16 + m16) * 64;
        offB[i] = (nb + i * 16 + m16) * 64;
    }

    const int NK = EMBED / 64;   // 16
#define STAGE(t) do {                                                        \
        unsigned short* la = As + ((t) & 1) * (128 * 64) + wv * 32 * 64;     \
        unsigned short* lb = Bs + ((t) & 1) * (128 * 64) + wv * 32 * 64;     \
        const unsigned short* gat = ga + (t) * 64;                           \
        const unsigned short* gbt = gb + (t) * 64;                           \
        _Pragma("unroll")                                                    \
        for (int j = 0; j < 4; ++j) {                                        \
            async16(gat + j * 8 * EMBED, la + j * 8 * 64);                   \
            async16(gbt + j * 8 * EMBED, lb + j * 8 * 64);                   \
        }                                                                    \
    } while (0)

    STAGE(0);
    for (int t = 0; t < NK; ++t) {
        if (t + 1 < NK) {
            STAGE(t + 1);
            asm volatile("s_waitcnt vmcnt(8)" ::: "memory");
        } else {
            asm volatile("s_waitcnt vmcnt(0)" ::: "memory");
        }
        asm volatile("s_barrier" ::: "memory");
        const unsigned short* Ab = As + (t & 1) * (128 * 64);
        const unsigned short* Bb = Bs + (t & 1) * (128 * 64);
#pragma unroll
        for (int ks = 0; ks < 2; ++ks) {
            const int sl = (((ks << 2) + quad) ^ rsw) << 3;
            bf16x8 af[4], bfv[4];
#pragma unroll
            for (int i = 0; i < 4; ++i) {
                af[i]  = *(const bf16x8*)(Ab + offA[i] + sl);
                bfv[i] = *(const bf16x8*)(Bb + offB[i] + sl);
            }
#pragma unroll
            for (int i = 0; i < 4; ++i)
#pragma unroll
                for (int j = 0; j < 4; ++j)
                    acc[i][j] = __builtin_amdgcn_mfma_f32_16x16x32_bf16(
                        af[i], bfv[j], acc[i][j], 0, 0, 0);
        }
        asm volatile("s_barrier" ::: "memory");
    }
#undef STAGE
}

// ---------------------------------------------------------------------------
// MFMA GEMM core 128x64 (out_gemm), same treatment. 6 loads/K-step.
// ---------------------------------------------------------------------------
__device__ __forceinline__ void mfma_gemm_core64(
    const unsigned short* __restrict__ A, const unsigned short* __restrict__ Bt,
    int bm, int n0, unsigned short* As, unsigned short* Bs,
    int wv, int lane, f32x4 acc[4][2])
{
    const int m16 = lane & 15, quad = lane >> 4;
    const int mb = (wv >> 1) << 6;
    const int nb = (wv & 1) << 5;
    const int rsw = m16 & 7;

    const int gcol = ((lane & 7) ^ ((lane >> 3) & 7)) << 3;
    const unsigned short* ga = A  + (size_t)(bm + wv * 32 + (lane >> 3)) * EMBED + gcol;
    const unsigned short* gb = Bt + (size_t)(n0 + wv * 16 + (lane >> 3)) * EMBED + gcol;

    int offA[4], offB[2];
#pragma unroll
    for (int i = 0; i < 4; ++i) offA[i] = (mb + i * 16 + m16) * 64;
#pragma unroll
    for (int j = 0; j < 2; ++j) offB[j] = (nb + j * 16 + m16) * 64;

    const int NK = EMBED / 64;
#define STAGE64(t) do {                                                      \
        unsigned short* la = As + ((t) & 1) * (128 * 64) + wv * 32 * 64;     \
        unsigned short* lb = Bs + ((t) & 1) * (64 * 64) + wv * 16 * 64;      \
        const unsigned short* gat = ga + (t) * 64;                           \
        const unsigned short* gbt = gb + (t) * 64;                           \
        _Pragma("unroll")                                                    \
        for (int j = 0; j < 4; ++j)                                          \
            async16(gat + j * 8 * EMBED, la + j * 8 * 64);                   \
        _Pragma("unroll")                                                    \
        for (int j = 0; j < 2; ++j)                                          \
            async16(gbt + j * 8 * EMBED, lb + j * 8 * 64);                   \
    } while (0)

    STAGE64(0);
    for (int t = 0; t < NK; ++t) {
        if (t + 1 < NK) {
            STAGE64(t + 1);
            asm volatile("s_waitcnt vmcnt(6)" ::: "memory");
        } else {
            asm volatile("s_waitcnt vmcnt(0)" ::: "memory");
        }
        asm volatile("s_barrier" ::: "memory");
        const unsigned short* Ab = As + (t & 1) * (128 * 64);
        const unsigned short* Bb = Bs + (t & 1) * (64 * 64);
#pragma unroll
        for (int ks = 0; ks < 2; ++ks) {
            const int sl = (((ks << 2) + quad) ^ rsw) << 3;
            bf16x8 af[4], bfv[2];
#pragma unroll
            for (int i = 0; i < 4; ++i)
                af[i] = *(const bf16x8*)(Ab + offA[i] + sl);
#pragma unroll
            for (int j = 0; j < 2; ++j)
                bfv[j] = *(const bf16x8*)(Bb + offB[j] + sl);
#pragma unroll
            for (int i = 0; i < 4; ++i)
#pragma unroll
                for (int j = 0; j < 2; ++j)
                    acc[i][j] = __builtin_amdgcn_mfma_f32_16x16x32_bf16(
                        af[i], bfv[j], acc[i][j], 0, 0, 0);
        }
        asm volatile("s_barrier" ::: "memory");
    }
#undef STAGE64
}

// ---------------------------------------------------------------------------
// Fused QKV projection
// ---------------------------------------------------------------------------
__global__ __launch_bounds__(256)
void qkv_gemm(const unsigned short* __restrict__ xb,
              const unsigned short* __restrict__ Wtq,
              const unsigned short* __restrict__ Wtk,
              const unsigned short* __restrict__ Wtv,
              const float* __restrict__ bq, const float* __restrict__ bk,
              const float* __restrict__ bv,
              unsigned short* __restrict__ Qo, unsigned short* __restrict__ Ko,
              unsigned short* __restrict__ Vto)
{
    __shared__ __align__(16) unsigned short As[2 * 128 * 64];
    __shared__ __align__(16) unsigned short Bs[2 * 128 * 64];
    const int tid = threadIdx.x, wv = tid >> 6, lane = tid & 63;
    const int m16 = lane & 15, quad = lane >> 4;
    const int which = blockIdx.x >> 3;
    const int n0 = (blockIdx.x & 7) << 7;
    const int bm = blockIdx.y << 7;
    const unsigned short* Bt = which == 0 ? Wtq : which == 1 ? Wtk : Wtv;
    const float* bias = which == 0 ? bq : which == 1 ? bk : bv;

    f32x4 acc[4][4];
#pragma unroll
    for (int i = 0; i < 4; ++i)
#pragma unroll
        for (int j = 0; j < 4; ++j) acc[i][j] = (f32x4){0.f, 0.f, 0.f, 0.f};

    mfma_gemm_core(xb, Bt, bm, n0, As, Bs, wv, lane, acc);

    const int mb = (wv >> 1) << 6, nb = (wv & 1) << 6;
    const float qscale = 0.125f * 1.4426950408889634f;
#pragma unroll
    for (int i = 0; i < 4; ++i) {
        const int m0 = bm + mb + i * 16 + quad * 4;
        const int b = m0 >> 11, t0 = m0 & (SEQ - 1);
#pragma unroll
        for (int j = 0; j < 4; ++j) {
            const int n = n0 + nb + j * 16 + m16;
            const int h = n >> 6, d = n & 63;
            const float bval = bias[n];
            if (which == 2) {
                us4 v;
#pragma unroll
                for (int r = 0; r < 4; ++r) v[r] = f2bf(acc[i][j][r] + bval);
                *(us4*)(Vto + ((((size_t)(b * NHEADS + h)) << 6) + d) * SEQ + t0) = v;
            } else {
                const float sc = which == 0 ? qscale : 1.f;
                unsigned short* dst = (which == 0 ? Qo : Ko) +
                    ((((size_t)(b * NHEADS + h)) << 11) + t0) * 64 + d;
#pragma unroll
                for (int r = 0; r < 4; ++r)
                    dst[(size_t)r * 64] = f2bf((acc[i][j][r] + bval) * sc);
            }
        }
    }
}

// ---------------------------------------------------------------------------
// Output projection: out fp32 = ao_bf16 @ Wo + bo. 128x64 tile, 512 blocks.
// ---------------------------------------------------------------------------
__global__ __launch_bounds__(256)
void out_gemm(const unsigned short* __restrict__ aob,
              const unsigned short* __restrict__ Wto,
              const float* __restrict__ bo, float* __restrict__ out)
{
    __shared__ __align__(16) unsigned short As[2 * 128 * 64];
    __shared__ __align__(16) unsigned short Bs[2 * 64 * 64];
    const int tid = threadIdx.x, wv = tid >> 6, lane = tid & 63;
    const int m16 = lane & 15, quad = lane >> 4;
    const int n0 = blockIdx.x << 6;
    const int bm = blockIdx.y << 7;

    f32x4 acc[4][2];
#pragma unroll
    for (int i = 0; i < 4; ++i)
#pragma unroll
        for (int j = 0; j < 2; ++j) acc[i][j] = (f32x4){0.f, 0.f, 0.f, 0.f};

    mfma_gemm_core64(aob, Wto, bm, n0, As, Bs, wv, lane, acc);

    const int mb = (wv >> 1) << 6, nb = (wv & 1) << 5;
#pragma unroll
    for (int i = 0; i < 4; ++i) {
        const int m0 = bm + mb + i * 16 + quad * 4;
#pragma unroll
        for (int j = 0; j < 2; ++j) {
            const int n = n0 + nb + j * 16 + m16;
            const float bval = bo[n];
#pragma unroll
            for (int r = 0; r < 4; ++r)
                out[(size_t)(m0 + r) * EMBED + n] = acc[i][j][r] + bval;
        }
    }
}

// ---------------------------------------------------------------------------
// bf16 MFMA flash attention (unchanged)
// ---------------------------------------------------------------------------
__global__ __launch_bounds__(256)
void attn_mfma(const unsigned short* __restrict__ Qb,
               const unsigned short* __restrict__ Kb,
               const unsigned short* __restrict__ Vtb,
               unsigned short* __restrict__ Oout)
{
    __shared__ __align__(16) unsigned short Ks[2][64 * 64];   // [key][d]  swz
    __shared__ __align__(16) unsigned short Vt[2][64 * 64];   // [d][key]  swz
    __shared__ __align__(16) unsigned short Ps[4][16 * 64];   // [query][key] swz

    const int tid  = threadIdx.x;
    const int wv   = tid >> 6;
    const int lane = tid & 63;
    const int m16  = lane & 15;
    const int quad = lane >> 4;
    const int bh   = blockIdx.x;
    const int b    = bh >> 4, h = bh & 15;

    // balanced qt permutation: y = r + 8k -> qt in {r, 15-r, 16+r, 31-r}
    const int yr = blockIdx.y & 7, yk = blockIdx.y >> 3;
    const int qt = yk == 0 ? yr : yk == 1 ? 15 - yr : yk == 2 ? 16 + yr : 31 - yr;
    const int q0 = qt << 6;

    const int srow = tid >> 2;         // 0..63
    const int cc   = tid & 3;          // 16B-slot pair index
    const int swr  = srow & 7;         // write-side swizzle
    const int sx   = m16 & 7;          // read-side swizzle (row % 8)

    bf16x8 rk0, rk1, rv0, rv1;
    auto load_tile = [&](int k0) {
        const int scol = cc << 4;
        const unsigned short* sk = Kb + (((size_t)bh << 11) + k0 + srow) * 64 + scol;
        rk0 = *(const bf16x8*)sk;
        rk1 = *(const bf16x8*)(sk + 8);
        const unsigned short* sv = Vtb + (((size_t)bh << 6) + srow) * SEQ + k0 + scol;
        rv0 = *(const bf16x8*)sv;
        rv1 = *(const bf16x8*)(sv + 8);
    };

    // Q fragment (B operand): lane n = query = m16, k = d
    const size_t qoff =
        (((size_t)bh << 11) + q0 + (wv << 4) + m16) * 64 + (quad << 3);
    bf16x8 qa0 = *(const bf16x8*)(Qb + qoff);
    bf16x8 qa1 = *(const bf16x8*)(Qb + qoff + 32);

    f32x4 o[4];
#pragma unroll
    for (int dt = 0; dt < 4; ++dt) o[dt] = (f32x4){0.f, 0.f, 0.f, 0.f};
    float m_ = -1e30f, l_ = 0.f;

    load_tile(0);

    for (int kt = 0; kt <= qt; ++kt) {
        unsigned short* Kp = Ks[kt & 1];
        unsigned short* Vp = Vt[kt & 1];
        {
            unsigned short* kd = Kp + srow * 64;
            unsigned short* vd = Vp + srow * 64;
            *(bf16x8*)(kd + (((2 * cc) ^ swr) << 3))     = rk0;
            *(bf16x8*)(kd + (((2 * cc + 1) ^ swr) << 3)) = rk1;
            *(bf16x8*)(vd + (((2 * cc) ^ swr) << 3))     = rv0;
            *(bf16x8*)(vd + (((2 * cc + 1) ^ swr) << 3)) = rv1;
        }
        __syncthreads();
        if (kt < qt) load_tile((kt + 1) << 6);

        const bool diag = (kt == qt);

        // S^T = K·Q^T: D[key=g*16+quad*4+r][query=m16]
        f32x4 s[4];
#pragma unroll
        for (int g = 0; g < 4; ++g) {
            if (diag && g > wv) {
                s[g] = (f32x4){-1e30f, -1e30f, -1e30f, -1e30f};
                continue;
            }
            const unsigned short* kr = Kp + (g * 16 + m16) * 64;
            bf16x8 kb0 = *(const bf16x8*)(kr + ((quad ^ sx) << 3));
            bf16x8 kb1 = *(const bf16x8*)(kr + (((quad + 4) ^ sx) << 3));
            s[g] = (f32x4){0.f, 0.f, 0.f, 0.f};
            s[g] = __builtin_amdgcn_mfma_f32_16x16x32_bf16(kb0, qa0, s[g], 0, 0, 0);
            s[g] = __builtin_amdgcn_mfma_f32_16x16x32_bf16(kb1, qa1, s[g], 0, 0, 0);
        }
        if (diag) {
#pragma unroll
            for (int r = 0; r < 4; ++r)
                if (quad * 4 + r > m16) s[wv][r] = -1e30f;
        }

        // online softmax; all 16 scores belong to query m16
        float mx = fmaxf(fmaxf(s[0][0], s[0][1]), fmaxf(s[0][2], s[0][3]));
#pragma unroll
        for (int g = 1; g < 4; ++g)
            mx = fmaxf(mx, fmaxf(fmaxf(s[g][0], s[g][1]), fmaxf(s[g][2], s[g][3])));
        mx = fmaxf(mx, __shfl_xor(mx, 16));
        mx = fmaxf(mx, __shfl_xor(mx, 32));

        // defer-max: only rescale when tile max grows by > 8 (P bounded 2^8)
        if (mx > m_ + 8.f) {
            const float alpha = exp2f(m_ - mx);
            m_ = mx;
            l_ *= alpha;
#pragma unroll
            for (int dt = 0; dt < 4; ++dt) o[dt] *= alpha;
        }

        float sum = 0.f;
        unsigned int pw0[4], pw1[4];
#pragma unroll
        for (int g = 0; g < 4; ++g) {
            float p0 = exp2f(s[g][0] - m_);
            float p1 = exp2f(s[g][1] - m_);
            float p2 = exp2f(s[g][2] - m_);
            float p3 = exp2f(s[g][3] - m_);
            sum += (p0 + p1) + (p2 + p3);
            pw0[g] = cvt_pk_bf16(p0, p1);
            pw1[g] = cvt_pk_bf16(p2, p3);
        }
        sum += __shfl_xor(sum, 16);
        sum += __shfl_xor(sum, 32);
        l_ += sum;

        // P^T -> Ps[query][key]
        {
            unsigned short* pd = Ps[wv] + m16 * 64 + ((quad & 1) << 2);
#pragma unroll
            for (int g = 0; g < 4; ++g) {
                u32x2 w; w.x = pw0[g]; w.y = pw1[g];
                *(u32x2*)(pd + (((2 * g + (quad >> 1)) ^ sx) << 3)) = w;
            }
        }

        // O^T += V^T·P^T: A = V^T-frag, B = P^T-frag
        const unsigned short* pr = Ps[wv] + m16 * 64;
        bf16x8 pa0 = *(const bf16x8*)(pr + ((quad ^ sx) << 3));
        bf16x8 pa1 = *(const bf16x8*)(pr + (((quad + 4) ^ sx) << 3));
        const bool skip_hi = diag && (wv < 2);   // keys 32..63 all masked
#pragma unroll
        for (int dt = 0; dt < 4; ++dt) {
            const unsigned short* vr = Vp + (dt * 16 + m16) * 64;
            bf16x8 vb0 = *(const bf16x8*)(vr + ((quad ^ sx) << 3));
            o[dt] = __builtin_amdgcn_mfma_f32_16x16x32_bf16(vb0, pa0, o[dt], 0, 0, 0);
            if (!skip_hi) {
                bf16x8 vb1 = *(const bf16x8*)(vr + (((quad + 4) ^ sx) << 3));
                o[dt] = __builtin_amdgcn_mfma_f32_16x16x32_bf16(vb1, pa1, o[dt], 0, 0, 0);
            }
        }
    }

    // epilogue: lane m16 = query t, holds d = dt*16 + quad*4 + r
    const float inv = 1.f / l_;
    const int t = q0 + (wv << 4) + m16;
    unsigned short* dst =
        Oout + ((size_t)((b << 11) + t) << 10) + (h << 6) + (quad << 2);
#pragma unroll
    for (int dt = 0; dt < 4; ++dt) {
        u32x2 w;
        w.x = cvt_pk_bf16(o[dt][0] * inv, o[dt][1] * inv);
        w.y = cvt_pk_bf16(o[dt][2] * inv, o[dt][3] * inv);
        *(u32x2*)(dst + dt * 16) = w;
    }
}

extern "C" void kernel_launch(void* const* d_in, const int* in_sizes, int n_in,
                              void* d_out, int out_size, void* d_ws, size_t ws_size,
                              hipStream_t stream) {
    const float* x  = (const float*)d_in[0];
    const float* Wq = (const float*)d_in[1];
    const float* bq = (const float*)d_in[2];
    const float* Wk = (const float*)d_in[3];
    const float* bk = (const float*)d_in[4];
    const float* Wv = (const float*)d_in[5];
    const float* bv = (const float*)d_in[6];
    const float* Wo = (const float*)d_in[7];
    const float* bo = (const float*)d_in[8];
    float* out = (float*)d_out;

    const size_t HSZ = (size_t)MROWS * EMBED;   // 4M elems
    const size_t WSZ = (size_t)EMBED * EMBED;   // 1M elems
    unsigned short* qb  = (unsigned short*)d_ws;
    unsigned short* kb  = qb + HSZ;
    unsigned short* vtb = kb + HSZ;
    unsigned short* aob = vtb + HSZ;
    unsigned short* xb  = aob + HSZ;
    unsigned short* wtq = xb + HSZ;
    unsigned short* wtk = wtq + WSZ;
    unsigned short* wtv = wtk + WSZ;
    unsigned short* wto = wtv + WSZ;

    cvt_x<<<MROWS * EMBED / 1024, 256, 0, stream>>>(x, xb);
    cvt_w<<<dim3(16, 16, 4), 256, 0, stream>>>(Wq, Wk, Wv, Wo, wtq, wtk, wtv, wto);

    qkv_gemm<<<dim3(24, 32), 256, 0, stream>>>(xb, wtq, wtk, wtv, bq, bk, bv,
                                               qb, kb, vtb);

    attn_mfma<<<dim3(32, 32), 256, 0, stream>>>(qb, kb, vtb, aob);

    out_gemm<<<dim3(16, 32), 256, 0, stream>>>(aob, wto, bo, out);
}

// Round 4
// 195.962 us; speedup vs baseline: 1.1541x; 1.0351x over previous
//
#include <hip/hip_runtime.h>

#define EMBED 1024
#define NHEADS 16
#define HDIM 64
#define SEQ 2048
#define BATCH 2
#define MROWS (BATCH * SEQ)   // 4096

using bf16x8 = __attribute__((ext_vector_type(8))) short;
using f32x4  = __attribute__((ext_vector_type(4))) float;
using us4    = __attribute__((ext_vector_type(4))) unsigned short;
using u32x2  = __attribute__((ext_vector_type(2))) unsigned int;

__device__ __forceinline__ unsigned short f2bf(float f) {
    unsigned int u = __builtin_bit_cast(unsigned int, f);
    u = (u + 0x7fffu + ((u >> 16) & 1u)) >> 16;   // RNE
    return (unsigned short)u;
}

// HW packed f32->bf16 (RNE). No builtin on gfx950 -> inline asm.
__device__ __forceinline__ unsigned int cvt_pk_bf16(float a, float b) {
    unsigned int d;
    asm("v_cvt_pk_bf16_f32 %0, %1, %2" : "=v"(d) : "v"(a), "v"(b));
    return d;
}

__device__ __forceinline__ void async16(const unsigned short* g, unsigned short* l) {
    __builtin_amdgcn_global_load_lds(
        (const __attribute__((address_space(1))) void*)g,
        (__attribute__((address_space(3))) void*)l, 16, 0, 0);
}

// ---------------------------------------------------------------------------
// fused converts: z<4 -> cvt_w (W fp32 [k][n] -> Wt bf16 [n][k], 64x64 tile);
// z==4 -> cvt_x grid-stride (fp32 -> bf16, 4 elems/thread, 16 iters/block).
// ---------------------------------------------------------------------------
__global__ __launch_bounds__(256)
void cvt_all(const float* __restrict__ X, unsigned short* __restrict__ XO,
             const float* __restrict__ W0, const float* __restrict__ W1,
             const float* __restrict__ W2, const float* __restrict__ W3,
             unsigned short* __restrict__ T0, unsigned short* __restrict__ T1,
             unsigned short* __restrict__ T2, unsigned short* __restrict__ T3)
{
    const int tid = threadIdx.x;
    if (blockIdx.z == 4) {
        // x convert: 256 blocks (16x16 xy) x 256 thr x 4 elems x 16 iters
        const int blk = blockIdx.y * 16 + blockIdx.x;
#pragma unroll
        for (int it = 0; it < 16; ++it) {
            int i = (blk * 16 + it) * 256 + tid;
            float4 v = ((const float4*)X)[i];
            us4 o;
            o[0] = f2bf(v.x); o[1] = f2bf(v.y); o[2] = f2bf(v.z); o[3] = f2bf(v.w);
            ((us4*)XO)[i] = o;
        }
        return;
    }
    const float* W = blockIdx.z == 0 ? W0 : blockIdx.z == 1 ? W1 :
                     blockIdx.z == 2 ? W2 : W3;
    unsigned short* T = blockIdx.z == 0 ? T0 : blockIdx.z == 1 ? T1 :
                        blockIdx.z == 2 ? T2 : T3;
    __shared__ unsigned short tile[64][72];
    const int k0 = blockIdx.y << 6, n0 = blockIdx.x << 6;
    const int lr = tid >> 4, lc = (tid & 15) << 2;
#pragma unroll
    for (int it = 0; it < 4; ++it) {
        int kr = lr + it * 16;
        float4 v = *(const float4*)(W + (size_t)(k0 + kr) * EMBED + n0 + lc);
        tile[lc + 0][kr] = f2bf(v.x);
        tile[lc + 1][kr] = f2bf(v.y);
        tile[lc + 2][kr] = f2bf(v.z);
        tile[lc + 3][kr] = f2bf(v.w);
    }
    __syncthreads();
#pragma unroll
    for (int it = 0; it < 4; ++it) {
        int nr = lr + it * 16;
        us4 o = *(const us4*)(&tile[nr][lc]);
        *(us4*)(T + (size_t)(n0 + nr) * EMBED + k0 + lc) = o;
    }
}

// ---------------------------------------------------------------------------
// MFMA GEMM core 128x128, BK=32 double-buffer (32 KB LDS -> 5 blocks/CU cap;
// grid 3/CU fully co-resident, no dispatch tail). Counted vmcnt(4) keeps
// next-stage loads in flight across raw s_barrier. XOR-swizzle both-sides:
// source col (lane&3)^((lane>>2)&3), read slot quad^(m16&3) -> conflict-free
// ds_read_b128 (verified 0 conflicts with the same scheme at BK=64).
// ---------------------------------------------------------------------------
__device__ __forceinline__ void mfma_gemm_core(
    const unsigned short* __restrict__ A, const unsigned short* __restrict__ Bt,
    int bm, int n0, unsigned short* As, unsigned short* Bs,
    int wv, int lane, f32x4 acc[4][4])
{
    const int m16 = lane & 15, quad = lane >> 4;
    const int mb = (wv >> 1) << 6;
    const int nb = (wv & 1) << 6;
    const int rsw = m16 & 3;               // read-side swizzle (row & 3)

    // stage geometry: 64 lanes = 16 rows x 4 slots of 8 elems (16B).
    const int srow0 = lane >> 2;           // 0..15
    const int gcol  = ((lane & 3) ^ (srow0 & 3)) << 3;   // pre-swizzled source
    const unsigned short* ga = A  + (size_t)(bm + wv * 16 + srow0) * EMBED + gcol;
    const unsigned short* gb = Bt + (size_t)(n0 + wv * 16 + srow0) * EMBED + gcol;

    int offA[4], offB[4];
#pragma unroll
    for (int i = 0; i < 4; ++i) {
        offA[i] = (mb + i * 16 + m16) * 32;
        offB[i] = (nb + i * 16 + m16) * 32;
    }

    const int NK = EMBED / 32;   // 32
#define STAGE(t) do {                                                        \
        unsigned short* la = As + ((t) & 1) * (128 * 32) + wv * 16 * 32;     \
        unsigned short* lb = Bs + ((t) & 1) * (128 * 32) + wv * 16 * 32;     \
        const unsigned short* gat = ga + (t) * 32;                           \
        const unsigned short* gbt = gb + (t) * 32;                           \
        async16(gat, la);                                                    \
        async16(gat + 64 * EMBED, la + 64 * 32);                             \
        async16(gbt, lb);                                                    \
        async16(gbt + 64 * EMBED, lb + 64 * 32);                             \
    } while (0)

    STAGE(0);
    for (int t = 0; t < NK; ++t) {
        if (t + 1 < NK) {
            STAGE(t + 1);
            asm volatile("s_waitcnt vmcnt(4)" ::: "memory");
        } else {
            asm volatile("s_waitcnt vmcnt(0)" ::: "memory");
        }
        asm volatile("s_barrier" ::: "memory");
        const unsigned short* Ab = As + (t & 1) * (128 * 32);
        const unsigned short* Bb = Bs + (t & 1) * (128 * 32);
        const int sl = ((quad ^ rsw) << 3);
        bf16x8 af[4], bfv[4];
#pragma unroll
        for (int i = 0; i < 4; ++i) {
            af[i]  = *(const bf16x8*)(Ab + offA[i] + sl);
            bfv[i] = *(const bf16x8*)(Bb + offB[i] + sl);
        }
#pragma unroll
        for (int i = 0; i < 4; ++i)
#pragma unroll
            for (int j = 0; j < 4; ++j)
                acc[i][j] = __builtin_amdgcn_mfma_f32_16x16x32_bf16(
                    af[i], bfv[j], acc[i][j], 0, 0, 0);
        asm volatile("s_barrier" ::: "memory");
    }
#undef STAGE
}

// ---------------------------------------------------------------------------
// MFMA GEMM core 128x64 (out_gemm), BK=64 dbuf (unchanged; already 2/CU
// co-resident with its 512-block grid).
// ---------------------------------------------------------------------------
__device__ __forceinline__ void mfma_gemm_core64(
    const unsigned short* __restrict__ A, const unsigned short* __restrict__ Bt,
    int bm, int n0, unsigned short* As, unsigned short* Bs,
    int wv, int lane, f32x4 acc[4][2])
{
    const int m16 = lane & 15, quad = lane >> 4;
    const int mb = (wv >> 1) << 6;
    const int nb = (wv & 1) << 5;
    const int rsw = m16 & 7;

    const int gcol = ((lane & 7) ^ ((lane >> 3) & 7)) << 3;
    const unsigned short* ga = A  + (size_t)(bm + wv * 32 + (lane >> 3)) * EMBED + gcol;
    const unsigned short* gb = Bt + (size_t)(n0 + wv * 16 + (lane >> 3)) * EMBED + gcol;

    int offA[4], offB[2];
#pragma unroll
    for (int i = 0; i < 4; ++i) offA[i] = (mb + i * 16 + m16) * 64;
#pragma unroll
    for (int j = 0; j < 2; ++j) offB[j] = (nb + j * 16 + m16) * 64;

    const int NK = EMBED / 64;
#define STAGE64(t) do {                                                      \
        unsigned short* la = As + ((t) & 1) * (128 * 64) + wv * 32 * 64;     \
        unsigned short* lb = Bs + ((t) & 1) * (64 * 64) + wv * 16 * 64;      \
        const unsigned short* gat = ga + (t) * 64;                           \
        const unsigned short* gbt = gb + (t) * 64;                           \
        _Pragma("unroll")                                                    \
        for (int j = 0; j < 4; ++j)                                          \
            async16(gat + j * 8 * EMBED, la + j * 8 * 64);                   \
        _Pragma("unroll")                                                    \
        for (int j = 0; j < 2; ++j)                                          \
            async16(gbt + j * 8 * EMBED, lb + j * 8 * 64);                   \
    } while (0)

    STAGE64(0);
    for (int t = 0; t < NK; ++t) {
        if (t + 1 < NK) {
            STAGE64(t + 1);
            asm volatile("s_waitcnt vmcnt(6)" ::: "memory");
        } else {
            asm volatile("s_waitcnt vmcnt(0)" ::: "memory");
        }
        asm volatile("s_barrier" ::: "memory");
        const unsigned short* Ab = As + (t & 1) * (128 * 64);
        const unsigned short* Bb = Bs + (t & 1) * (64 * 64);
#pragma unroll
        for (int ks = 0; ks < 2; ++ks) {
            const int sl = (((ks << 2) + quad) ^ rsw) << 3;
            bf16x8 af[4], bfv[2];
#pragma unroll
            for (int i = 0; i < 4; ++i)
                af[i] = *(const bf16x8*)(Ab + offA[i] + sl);
#pragma unroll
            for (int j = 0; j < 2; ++j)
                bfv[j] = *(const bf16x8*)(Bb + offB[j] + sl);
#pragma unroll
            for (int i = 0; i < 4; ++i)
#pragma unroll
                for (int j = 0; j < 2; ++j)
                    acc[i][j] = __builtin_amdgcn_mfma_f32_16x16x32_bf16(
                        af[i], bfv[j], acc[i][j], 0, 0, 0);
        }
        asm volatile("s_barrier" ::: "memory");
    }
#undef STAGE64
}

// ---------------------------------------------------------------------------
// Fused QKV projection
// ---------------------------------------------------------------------------
__global__ __launch_bounds__(256)
void qkv_gemm(const unsigned short* __restrict__ xb,
              const unsigned short* __restrict__ Wtq,
              const unsigned short* __restrict__ Wtk,
              const unsigned short* __restrict__ Wtv,
              const float* __restrict__ bq, const float* __restrict__ bk,
              const float* __restrict__ bv,
              unsigned short* __restrict__ Qo, unsigned short* __restrict__ Ko,
              unsigned short* __restrict__ Vto)
{
    __shared__ __align__(16) unsigned short As[2 * 128 * 32];
    __shared__ __align__(16) unsigned short Bs[2 * 128 * 32];
    const int tid = threadIdx.x, wv = tid >> 6, lane = tid & 63;
    const int m16 = lane & 15, quad = lane >> 4;
    const int which = blockIdx.x >> 3;
    const int n0 = (blockIdx.x & 7) << 7;
    const int bm = blockIdx.y << 7;
    const unsigned short* Bt = which == 0 ? Wtq : which == 1 ? Wtk : Wtv;
    const float* bias = which == 0 ? bq : which == 1 ? bk : bv;

    f32x4 acc[4][4];
#pragma unroll
    for (int i = 0; i < 4; ++i)
#pragma unroll
        for (int j = 0; j < 4; ++j) acc[i][j] = (f32x4){0.f, 0.f, 0.f, 0.f};

    mfma_gemm_core(xb, Bt, bm, n0, As, Bs, wv, lane, acc);

    const int mb = (wv >> 1) << 6, nb = (wv & 1) << 6;
    const float qscale = 0.125f * 1.4426950408889634f;
#pragma unroll
    for (int i = 0; i < 4; ++i) {
        const int m0 = bm + mb + i * 16 + quad * 4;
        const int b = m0 >> 11, t0 = m0 & (SEQ - 1);
#pragma unroll
        for (int j = 0; j < 4; ++j) {
            const int n = n0 + nb + j * 16 + m16;
            const int h = n >> 6, d = n & 63;
            const float bval = bias[n];
            if (which == 2) {
                us4 v;
#pragma unroll
                for (int r = 0; r < 4; ++r) v[r] = f2bf(acc[i][j][r] + bval);
                *(us4*)(Vto + ((((size_t)(b * NHEADS + h)) << 6) + d) * SEQ + t0) = v;
            } else {
                const float sc = which == 0 ? qscale : 1.f;
                unsigned short* dst = (which == 0 ? Qo : Ko) +
                    ((((size_t)(b * NHEADS + h)) << 11) + t0) * 64 + d;
#pragma unroll
                for (int r = 0; r < 4; ++r)
                    dst[(size_t)r * 64] = f2bf((acc[i][j][r] + bval) * sc);
            }
        }
    }
}

// ---------------------------------------------------------------------------
// Output projection: out fp32 = ao_bf16 @ Wo + bo. 128x64 tile, 512 blocks.
// ---------------------------------------------------------------------------
__global__ __launch_bounds__(256)
void out_gemm(const unsigned short* __restrict__ aob,
              const unsigned short* __restrict__ Wto,
              const float* __restrict__ bo, float* __restrict__ out)
{
    __shared__ __align__(16) unsigned short As[2 * 128 * 64];
    __shared__ __align__(16) unsigned short Bs[2 * 64 * 64];
    const int tid = threadIdx.x, wv = tid >> 6, lane = tid & 63;
    const int m16 = lane & 15, quad = lane >> 4;
    const int n0 = blockIdx.x << 6;
    const int bm = blockIdx.y << 7;

    f32x4 acc[4][2];
#pragma unroll
    for (int i = 0; i < 4; ++i)
#pragma unroll
        for (int j = 0; j < 2; ++j) acc[i][j] = (f32x4){0.f, 0.f, 0.f, 0.f};

    mfma_gemm_core64(aob, Wto, bm, n0, As, Bs, wv, lane, acc);

    const int mb = (wv >> 1) << 6, nb = (wv & 1) << 5;
#pragma unroll
    for (int i = 0; i < 4; ++i) {
        const int m0 = bm + mb + i * 16 + quad * 4;
#pragma unroll
        for (int j = 0; j < 2; ++j) {
            const int n = n0 + nb + j * 16 + m16;
            const float bval = bo[n];
#pragma unroll
            for (int r = 0; r < 4; ++r)
                out[(size_t)(m0 + r) * EMBED + n] = acc[i][j][r] + bval;
        }
    }
}

// ---------------------------------------------------------------------------
// bf16 MFMA flash attention. Round-6: SINGLE-buffered K/V (LDS 40->24 KB =>
// 6 blocks/CU, was ~3) with 2 barriers/iter; register prefetch of next K/V
// tile still covers global latency across the whole compute phase.
// ---------------------------------------------------------------------------
__global__ __launch_bounds__(256)
void attn_mfma(const unsigned short* __restrict__ Qb,
               const unsigned short* __restrict__ Kb,
               const unsigned short* __restrict__ Vtb,
               unsigned short* __restrict__ Oout)
{
    __shared__ __align__(16) unsigned short Ks[64 * 64];      // [key][d]  swz
    __shared__ __align__(16) unsigned short Vt[64 * 64];      // [d][key]  swz
    __shared__ __align__(16) unsigned short Ps[4][16 * 64];   // [query][key] swz

    const int tid  = threadIdx.x;
    const int wv   = tid >> 6;
    const int lane = tid & 63;
    const int m16  = lane & 15;
    const int quad = lane >> 4;
    const int bh   = blockIdx.x;
    const int b    = bh >> 4, h = bh & 15;

    // balanced qt permutation: y = r + 8k -> qt in {r, 15-r, 16+r, 31-r}
    const int yr = blockIdx.y & 7, yk = blockIdx.y >> 3;
    const int qt = yk == 0 ? yr : yk == 1 ? 15 - yr : yk == 2 ? 16 + yr : 31 - yr;
    const int q0 = qt << 6;

    const int srow = tid >> 2;         // 0..63
    const int cc   = tid & 3;          // 16B-slot pair index
    const int swr  = srow & 7;         // write-side swizzle
    const int sx   = m16 & 7;          // read-side swizzle (row % 8)

    bf16x8 rk0, rk1, rv0, rv1;
    auto load_tile = [&](int k0) {
        const int scol = cc << 4;
        const unsigned short* sk = Kb + (((size_t)bh << 11) + k0 + srow) * 64 + scol;
        rk0 = *(const bf16x8*)sk;
        rk1 = *(const bf16x8*)(sk + 8);
        const unsigned short* sv = Vtb + (((size_t)bh << 6) + srow) * SEQ + k0 + scol;
        rv0 = *(const bf16x8*)sv;
        rv1 = *(const bf16x8*)(sv + 8);
    };

    // Q fragment (B operand): lane n = query = m16, k = d
    const size_t qoff =
        (((size_t)bh << 11) + q0 + (wv << 4) + m16) * 64 + (quad << 3);
    bf16x8 qa0 = *(const bf16x8*)(Qb + qoff);
    bf16x8 qa1 = *(const bf16x8*)(Qb + qoff + 32);

    f32x4 o[4];
#pragma unroll
    for (int dt = 0; dt < 4; ++dt) o[dt] = (f32x4){0.f, 0.f, 0.f, 0.f};
    float m_ = -1e30f, l_ = 0.f;

    load_tile(0);

    for (int kt = 0; kt <= qt; ++kt) {
        __syncthreads();   // all waves done reading previous tile
        {
            unsigned short* kd = Ks + srow * 64;
            unsigned short* vd = Vt + srow * 64;
            *(bf16x8*)(kd + (((2 * cc) ^ swr) << 3))     = rk0;
            *(bf16x8*)(kd + (((2 * cc + 1) ^ swr) << 3)) = rk1;
            *(bf16x8*)(vd + (((2 * cc) ^ swr) << 3))     = rv0;
            *(bf16x8*)(vd + (((2 * cc + 1) ^ swr) << 3)) = rv1;
        }
        __syncthreads();   // writes visible
        if (kt < qt) load_tile((kt + 1) << 6);

        const bool diag = (kt == qt);

        // S^T = K·Q^T: D[key=g*16+quad*4+r][query=m16]
        f32x4 s[4];
#pragma unroll
        for (int g = 0; g < 4; ++g) {
            if (diag && g > wv) {
                s[g] = (f32x4){-1e30f, -1e30f, -1e30f, -1e30f};
                continue;
            }
            const unsigned short* kr = Ks + (g * 16 + m16) * 64;
            bf16x8 kb0 = *(const bf16x8*)(kr + ((quad ^ sx) << 3));
            bf16x8 kb1 = *(const bf16x8*)(kr + (((quad + 4) ^ sx) << 3));
            s[g] = (f32x4){0.f, 0.f, 0.f, 0.f};
            s[g] = __builtin_amdgcn_mfma_f32_16x16x32_bf16(kb0, qa0, s[g], 0, 0, 0);
            s[g] = __builtin_amdgcn_mfma_f32_16x16x32_bf16(kb1, qa1, s[g], 0, 0, 0);
        }
        if (diag) {
#pragma unroll
            for (int r = 0; r < 4; ++r)
                if (quad * 4 + r > m16) s[wv][r] = -1e30f;
        }

        // online softmax; all 16 scores belong to query m16
        float mx = fmaxf(fmaxf(s[0][0], s[0][1]), fmaxf(s[0][2], s[0][3]));
#pragma unroll
        for (int g = 1; g < 4; ++g)
            mx = fmaxf(mx, fmaxf(fmaxf(s[g][0], s[g][1]), fmaxf(s[g][2], s[g][3])));
        mx = fmaxf(mx, __shfl_xor(mx, 16));
        mx = fmaxf(mx, __shfl_xor(mx, 32));

        // defer-max: only rescale when tile max grows by > 8 (P bounded 2^8)
        if (mx > m_ + 8.f) {
            const float alpha = exp2f(m_ - mx);
            m_ = mx;
            l_ *= alpha;
#pragma unroll
            for (int dt = 0; dt < 4; ++dt) o[dt] *= alpha;
        }

        float sum = 0.f;
        unsigned int pw0[4], pw1[4];
#pragma unroll
        for (int g = 0; g < 4; ++g) {
            float p0 = exp2f(s[g][0] - m_);
            float p1 = exp2f(s[g][1] - m_);
            float p2 = exp2f(s[g][2] - m_);
            float p3 = exp2f(s[g][3] - m_);
            sum += (p0 + p1) + (p2 + p3);
            pw0[g] = cvt_pk_bf16(p0, p1);
            pw1[g] = cvt_pk_bf16(p2, p3);
        }
        sum += __shfl_xor(sum, 16);
        sum += __shfl_xor(sum, 32);
        l_ += sum;

        // P^T -> Ps[query][key]
        {
            unsigned short* pd = Ps[wv] + m16 * 64 + ((quad & 1) << 2);
#pragma unroll
            for (int g = 0; g < 4; ++g) {
                u32x2 w; w.x = pw0[g]; w.y = pw1[g];
                *(u32x2*)(pd + (((2 * g + (quad >> 1)) ^ sx) << 3)) = w;
            }
        }

        // O^T += V^T·P^T: A = V^T-frag, B = P^T-frag
        const unsigned short* pr = Ps[wv] + m16 * 64;
        bf16x8 pa0 = *(const bf16x8*)(pr + ((quad ^ sx) << 3));
        bf16x8 pa1 = *(const bf16x8*)(pr + (((quad + 4) ^ sx) << 3));
        const bool skip_hi = diag && (wv < 2);   // keys 32..63 all masked
#pragma unroll
        for (int dt = 0; dt < 4; ++dt) {
            const unsigned short* vr = Vt + (dt * 16 + m16) * 64;
            bf16x8 vb0 = *(const bf16x8*)(vr + ((quad ^ sx) << 3));
            o[dt] = __builtin_amdgcn_mfma_f32_16x16x32_bf16(vb0, pa0, o[dt], 0, 0, 0);
            if (!skip_hi) {
                bf16x8 vb1 = *(const bf16x8*)(vr + (((quad + 4) ^ sx) << 3));
                o[dt] = __builtin_amdgcn_mfma_f32_16x16x32_bf16(vb1, pa1, o[dt], 0, 0, 0);
            }
        }
    }

    // epilogue: lane m16 = query t, holds d = dt*16 + quad*4 + r
    const float inv = 1.f / l_;
    const int t = q0 + (wv << 4) + m16;
    unsigned short* dst =
        Oout + ((size_t)((b << 11) + t) << 10) + (h << 6) + (quad << 2);
#pragma unroll
    for (int dt = 0; dt < 4; ++dt) {
        u32x2 w;
        w.x = cvt_pk_bf16(o[dt][0] * inv, o[dt][1] * inv);
        w.y = cvt_pk_bf16(o[dt][2] * inv, o[dt][3] * inv);
        *(u32x2*)(dst + dt * 16) = w;
    }
}

extern "C" void kernel_launch(void* const* d_in, const int* in_sizes, int n_in,
                              void* d_out, int out_size, void* d_ws, size_t ws_size,
                              hipStream_t stream) {
    const float* x  = (const float*)d_in[0];
    const float* Wq = (const float*)d_in[1];
    const float* bq = (const float*)d_in[2];
    const float* Wk = (const float*)d_in[3];
    const float* bk = (const float*)d_in[4];
    const float* Wv = (const float*)d_in[5];
    const float* bv = (const float*)d_in[6];
    const float* Wo = (const float*)d_in[7];
    const float* bo = (const float*)d_in[8];
    float* out = (float*)d_out;

    const size_t HSZ = (size_t)MROWS * EMBED;   // 4M elems
    const size_t WSZ = (size_t)EMBED * EMBED;   // 1M elems
    unsigned short* qb  = (unsigned short*)d_ws;
    unsigned short* kb  = qb + HSZ;
    unsigned short* vtb = kb + HSZ;
    unsigned short* aob = vtb + HSZ;
    unsigned short* xb  = aob + HSZ;
    unsigned short* wtq = xb + HSZ;
    unsigned short* wtk = wtq + WSZ;
    unsigned short* wtv = wtk + WSZ;
    unsigned short* wto = wtv + WSZ;

    cvt_all<<<dim3(16, 16, 5), 256, 0, stream>>>(x, xb, Wq, Wk, Wv, Wo,
                                                 wtq, wtk, wtv, wto);

    qkv_gemm<<<dim3(24, 32), 256, 0, stream>>>(xb, wtq, wtk, wtv, bq, bk, bv,
                                               qb, kb, vtb);

    attn_mfma<<<dim3(32, 32), 256, 0, stream>>>(qb, kb, vtb, aob);

    out_gemm<<<dim3(16, 32), 256, 0, stream>>>(aob, wto, bo, out);
}